// Round 4
// baseline (217.067 us; speedup 1.0000x reference)
//
#include <hip/hip_runtime.h>
#include <math.h>

// ---------------- workspace layout (float offsets) ----------------
#define WS_XD     0u          // 256*4096          pooled-4 x, row-major
#define WS_S      1048576u    // 256               row sums of xd
#define WS_GPART  1048832u    // 64*128*128        Gram partials (K-split)
#define WS_G      2097408u    // 128*128           Gram region rows[0,128) cols rb-80
#define WS_COEF   2113792u    // 256*96            attn@v coefficients (xd rows 170..255)
#define WS_CONST  2138368u    // 256
#define WS_ATT    2138624u    // 256*4096          attention-1 output (B,C,64,64)
#define WS_FAC    3187200u    // 256               2 - sim
#define WS_ALPHA  7382016u    // 256
#define WS_BETA   7382272u    // 1
#define WS_NSTAT  7382273u    // 16 (T[8], nrm[8])
#define WS_P2     7382304u    // 16*64*18          attn2 softmax partials

__device__ __forceinline__ float bsum(float v, float* sd, int tid) {
    sd[tid] = v; __syncthreads();
    for (int off = 128; off > 0; off >>= 1) {
        if (tid < off) sd[tid] += sd[tid + off];
        __syncthreads();
    }
    float r = sd[0]; __syncthreads(); return r;
}
__device__ __forceinline__ float bmax(float v, float* sd, int tid) {
    sd[tid] = v; __syncthreads();
    for (int off = 128; off > 0; off >>= 1) {
        if (tid < off) sd[tid] = fmaxf(sd[tid], sd[tid + off]);
        __syncthreads();
    }
    float r = sd[0]; __syncthreads(); return r;
}

// ---------------- K1: 4x4 maxpool + row sums (+ noise row stats folded in) ----------------
__global__ __launch_bounds__(256) void k_pool4(const float* __restrict__ x,
                                               const int* __restrict__ nidx,
                                               float* __restrict__ ws) {
    __shared__ float sd[256];
    int r = blockIdx.x, tid = threadIdx.x;
    const float4* xr = (const float4*)x + (size_t)r * 16384;
    float* xd = ws + WS_XD + (size_t)r * 4096;
    float sum = 0.f, s = 0.f, ss = 0.f;
    for (int it = 0; it < 16; ++it) {
        int o = it * 256 + tid;
        int h = o >> 6, w = o & 63;
        float m = -INFINITY;
        #pragma unroll
        for (int p = 0; p < 4; ++p) {
            float4 v = xr[(4 * h + p) * 64 + w];
            m = fmaxf(m, fmaxf(fmaxf(v.x, v.y), fmaxf(v.z, v.w)));
            s  += v.x + v.y + v.z + v.w;
            ss += v.x*v.x + v.y*v.y + v.z*v.z + v.w*v.w;
        }
        xd[o] = m; sum += m;
    }
    float st = bsum(sum, sd, tid);
    if (tid == 0) ws[WS_S + r] = st;
    // noise stats (uniform branch: r is block-uniform)
    bool isn = false;
    #pragma unroll
    for (int n = 0; n < 8; ++n) isn = isn || (nidx[n] == r);
    if (isn) {
        float ts = bsum(s, sd, tid);
        float tss = bsum(ss, sd, tid);
        if (tid == 0) {
            for (int n = 0; n < 8; ++n)
                if (nidx[n] == r) { ws[WS_NSTAT + n] = ts; ws[WS_NSTAT + 8 + n] = sqrtf(tss); }
        }
    }
}

// ---------------- K2: Gram partials: rows[0,128) x cols[80,208), K-split 64 ----------------
__global__ __launch_bounds__(256) void k_gram(float* __restrict__ ws) {
    __shared__ __align__(16) float As[64][68];
    __shared__ __align__(16) float Bs[64][68];
    int tid = threadIdx.x, tx = tid & 15, ty = tid >> 4;
    int ra0 = blockIdx.y * 64, rb0 = 80 + blockIdx.x * 64, k0 = blockIdx.z * 64;
    const float4* xd4 = (const float4*)(ws + WS_XD);
    #pragma unroll
    for (int q = 0; q < 4; ++q) {
        int idx = q * 256 + tid;
        int row = idx >> 4, cf = idx & 15;
        float4 a = xd4[(size_t)(ra0 + row) * 1024 + (k0 >> 2) + cf];
        As[cf*4+0][row] = a.x; As[cf*4+1][row] = a.y; As[cf*4+2][row] = a.z; As[cf*4+3][row] = a.w;
        float4 b = xd4[(size_t)(rb0 + row) * 1024 + (k0 >> 2) + cf];
        Bs[cf*4+0][row] = b.x; Bs[cf*4+1][row] = b.y; Bs[cf*4+2][row] = b.z; Bs[cf*4+3][row] = b.w;
    }
    __syncthreads();
    float acc[4][4] = {};
    #pragma unroll 4
    for (int kk = 0; kk < 64; ++kk) {
        float4 a = *(const float4*)&As[kk][ty * 4];
        float4 b = *(const float4*)&Bs[kk][tx * 4];
        acc[0][0] += a.x*b.x; acc[0][1] += a.x*b.y; acc[0][2] += a.x*b.z; acc[0][3] += a.x*b.w;
        acc[1][0] += a.y*b.x; acc[1][1] += a.y*b.y; acc[1][2] += a.y*b.z; acc[1][3] += a.y*b.w;
        acc[2][0] += a.z*b.x; acc[2][1] += a.z*b.y; acc[2][2] += a.z*b.z; acc[2][3] += a.z*b.w;
        acc[3][0] += a.w*b.x; acc[3][1] += a.w*b.y; acc[3][2] += a.w*b.z; acc[3][3] += a.w*b.w;
    }
    float* gp = ws + WS_GPART + (size_t)blockIdx.z * 16384;
    #pragma unroll
    for (int i = 0; i < 4; ++i) {
        float4 o = make_float4(acc[i][0], acc[i][1], acc[i][2], acc[i][3]);
        *(float4*)&gp[(size_t)(ra0 + ty * 4 + i) * 128 + blockIdx.x * 64 + tx * 4] = o;
    }
}

// ---------------- K2b: reduce Gram partials ----------------
__global__ __launch_bounds__(256) void k_gred(float* __restrict__ ws) {
    int t = blockIdx.x * 256 + threadIdx.x;   // float4 index, 4096 total
    const float4* gp = (const float4*)(ws + WS_GPART);
    float4 s = make_float4(0.f, 0.f, 0.f, 0.f);
    for (int p = 0; p < 64; ++p) {
        float4 v = gp[(size_t)p * 4096 + t];
        s.x += v.x; s.y += v.y; s.z += v.z; s.w += v.w;
    }
    ((float4*)(ws + WS_G))[t] = s;
}

// ---------------- K3: masked softmax row -> coef/const ----------------
__global__ __launch_bounds__(256) void k_attn1(const int* __restrict__ labels,
                                               const float* __restrict__ w1,
                                               const float* __restrict__ b1,
                                               float* __restrict__ ws) {
    __shared__ float sd[256];
    __shared__ float attn_s[256];
    int i = blockIdx.x, tid = threadIdx.x;
    int labi = labels[i];
    bool validi = (labi != -1);
    int bi = (i >= 192) ? 1 : 0;
    int ji = i - bi * 192;
    int rq = bi * 64 + ji / 3;
    float wq = w1[ji], bq = b1[ji];
    int gk = 256 + tid;
    int bk = (gk >= 384) ? 2 : 1;
    int jk = gk - bk * 192;
    int rk = bk * 64 + jk / 3;
    float wk = w1[jk], bbk = b1[jk];
    int labj = labels[tid];
    bool allowed = validi && (labj == labi) && (labj != -1);
    float score = wq * wk * ws[WS_G + rq * 128 + (rk - 80)]
                + wq * bbk * ws[WS_S + rq]
                + wk * bq  * ws[WS_S + rk]
                + 4096.0f * bq * bbk;
    float sc = allowed ? score : -1e30f;
    float m = bmax(sc, sd, tid);
    float e = __expf(sc - m);
    float Z = bsum(e, sd, tid);
    float attn = validi ? (e / Z) : 0.0f;
    attn_s[tid] = attn;
    int gv = 512 + tid;
    int bv = (gv >= 576) ? 3 : 2;
    int jv = gv - bv * 192;
    float csum = bsum(attn * b1[jv], sd, tid);   // barrier also publishes attn_s
    if (tid < 96) {
        float s = 0.0f;
        if (tid < 86) {
            int rv = 170 + tid;
            int lo, hi, jadd;
            if (rv < 192) { int c = rv - 128; lo = 3 * c; if (lo < 128) lo = 128; hi = 3 * c + 2; jadd = -128; }
            else          { int c = rv - 192; lo = 3 * c; hi = 3 * c + 2; jadd = 64; }
            for (int jj = lo; jj <= hi; ++jj) s += attn_s[jj + jadd] * w1[jj];
        }
        ws[WS_COEF + i * 96 + tid] = s;
    }
    if (tid == 0) ws[WS_CONST + i] = csum;
}

// ---------------- K4: att = coef @ xd[170:256] + const ----------------
__global__ __launch_bounds__(256) void k_attmm(float* __restrict__ ws) {
    __shared__ __align__(16) float As[96][68];
    __shared__ __align__(16) float Bs[96][64];
    int tid = threadIdx.x, tx = tid & 15, ty = tid >> 4;
    int col0 = blockIdx.x * 64, row0 = blockIdx.y * 64;
    const float4* cf4 = (const float4*)(ws + WS_COEF);
    const float4* xd4 = (const float4*)(ws + WS_XD);
    #pragma unroll
    for (int q = 0; q < 6; ++q) {
        int f = q * 256 + tid;
        {
            int row = f / 24, c24 = f - row * 24;
            float4 v = cf4[(size_t)(row0 + row) * 24 + c24];
            As[c24*4+0][row] = v.x; As[c24*4+1][row] = v.y; As[c24*4+2][row] = v.z; As[c24*4+3][row] = v.w;
        }
        {
            int row = f >> 4, c16 = f & 15;
            float4 v = make_float4(0.f, 0.f, 0.f, 0.f);
            if (row < 86) v = xd4[(size_t)(170 + row) * 1024 + (col0 >> 2) + c16];
            *(float4*)&Bs[row][c16 * 4] = v;
        }
    }
    __syncthreads();
    float acc[4][4] = {};
    #pragma unroll 4
    for (int kk = 0; kk < 96; ++kk) {
        float4 a = *(const float4*)&As[kk][ty * 4];
        float4 b = *(const float4*)&Bs[kk][tx * 4];
        acc[0][0] += a.x*b.x; acc[0][1] += a.x*b.y; acc[0][2] += a.x*b.z; acc[0][3] += a.x*b.w;
        acc[1][0] += a.y*b.x; acc[1][1] += a.y*b.y; acc[1][2] += a.y*b.z; acc[1][3] += a.y*b.w;
        acc[2][0] += a.z*b.x; acc[2][1] += a.z*b.y; acc[2][2] += a.z*b.z; acc[2][3] += a.z*b.w;
        acc[3][0] += a.w*b.x; acc[3][1] += a.w*b.y; acc[3][2] += a.w*b.z; acc[3][3] += a.w*b.w;
    }
    float* att = ws + WS_ATT;
    #pragma unroll
    for (int i = 0; i < 4; ++i) {
        int row = row0 + ty * 4 + i;
        float cv = ws[WS_CONST + row];
        float4 o = make_float4(acc[i][0] + cv, acc[i][1] + cv, acc[i][2] + cv, acc[i][3] + cv);
        *(float4*)&att[(size_t)row * 4096 + col0 + tx * 4] = o;
    }
}

// ---------------- K5: sim(b,c) -> fac = 2 - sim ----------------
__global__ __launch_bounds__(256) void k_sim(const float* __restrict__ x,
                                             const int* __restrict__ nidx,
                                             const float* __restrict__ upk,
                                             const float* __restrict__ upb,
                                             float* __restrict__ ws) {
    __shared__ float sd[256];
    int r = blockIdx.x, tid = threadIdx.x;
    int b = r >> 6, c = r & 63;
    const float* att = ws + WS_ATT + (size_t)r * 4096;
    const float4* xn0 = (const float4*)x + (size_t)nidx[2 * b] * 16384;
    const float4* xn1 = (const float4*)x + (size_t)nidx[2 * b + 1] * 16384;
    const float4* k4p = (const float4*)upk + c * 4;
    float ub = upb[c];
    float4 kk0 = k4p[0], kk1 = k4p[1], kk2 = k4p[2], kk3 = k4p[3];
    float s2 = 0.f, d0 = 0.f, d1 = 0.f;
    for (int it = 0; it < 64; ++it) {
        int f = it * 256 + tid;
        int rowf = f >> 6, c4 = f & 63;
        float av = att[(rowf >> 2) * 64 + c4];
        int p = rowf & 3;
        float4 kv = (p == 0) ? kk0 : ((p == 1) ? kk1 : ((p == 2) ? kk2 : kk3));
        float4 a0 = xn0[f], a1 = xn1[f];
        float u;
        u = av * kv.x + ub; s2 += u * u; d0 += u * a0.x; d1 += u * a1.x;
        u = av * kv.y + ub; s2 += u * u; d0 += u * a0.y; d1 += u * a1.y;
        u = av * kv.z + ub; s2 += u * u; d0 += u * a0.z; d1 += u * a1.z;
        u = av * kv.w + ub; s2 += u * u; d0 += u * a0.w; d1 += u * a1.w;
    }
    s2 = bsum(s2, sd, tid);
    d0 = bsum(d0, sd, tid);
    d1 = bsum(d1, sd, tid);
    if (tid == 0) {
        float nup = fmaxf(sqrtf(s2), 1e-12f);
        float n0 = fmaxf(ws[WS_NSTAT + 8 + 2 * b], 1e-12f);
        float n1 = fmaxf(ws[WS_NSTAT + 8 + 2 * b + 1], 1e-12f);
        float sim = 0.5f * (d0 / (nup * n0) + d1 / (nup * n1));
        ws[WS_FAC + r] = 2.0f - sim;
    }
}

// ---------------- K6: fused out_clu -> group conv -> maxpool2 -> attn2 partials ----------------
// grid (64, 4) = (h2-pair hp, b); block 256. Thread owns pooled loc (h2, w).
__global__ __launch_bounds__(256) void k_cluat(const float* __restrict__ x,
                                               const float* __restrict__ upk,
                                               const float* __restrict__ upb,
                                               const float* __restrict__ cw,
                                               const float* __restrict__ cb,
                                               const float* __restrict__ w2,
                                               float* __restrict__ ws) {
    __shared__ float wcl[1024];   // clu_w[g][o][i] all groups
    __shared__ float kup[1024];   // up_k all channels
    __shared__ float cbl[64], ubl[64], fcl[64];
    __shared__ float wl2[192];
    __shared__ float red[4][4][18];   // [wave][nh][m,den,num16]
    int hp = blockIdx.x, b = blockIdx.y, t = threadIdx.x;
    #pragma unroll
    for (int q = 0; q < 4; ++q) {
        wcl[q * 256 + t] = cw[q * 256 + t];
        kup[q * 256 + t] = upk[q * 256 + t];
    }
    if (t < 64) {
        cbl[t] = cb[t];
        ubl[t] = upb[t];
        fcl[t] = ws[WS_FAC + b * 64 + t];
    }
    if (t < 192) wl2[t] = w2[t];
    __syncthreads();

    int h2 = hp * 2 + (t >> 7);
    int w = t & 127;
    int r0 = 2 * h2;                 // input row (even)
    int p0 = r0 & 3;                 // 0 or 2
    int q0 = (2 * w) & 3;            // 0 or 2
    int h_att = hp;                  // = h2>>1 for both rows of the pair
    int wa = w >> 1;

    const float* attb = ws + WS_ATT;
    float xv[64];                    // pooled group-conv outputs
    #pragma unroll
    for (int g = 0; g < 4; ++g) {
        float oc[16][4];
        #pragma unroll
        for (int i = 0; i < 16; ++i) {
            int ch = g * 16 + i;
            float av = attb[(size_t)(b * 64 + ch) * 4096 + h_att * 64 + wa];
            const float* xc = x + (size_t)(b * 64 + ch) * 65536;
            float2 x0 = *(const float2*)&xc[r0 * 256 + 2 * w];
            float2 x1 = *(const float2*)&xc[(r0 + 1) * 256 + 2 * w];
            float ub = ubl[ch], fc = fcl[ch];
            oc[i][0] = av * kup[ch * 16 + p0 * 4 + q0]       + ub + fc * x0.x;
            oc[i][1] = av * kup[ch * 16 + p0 * 4 + q0 + 1]   + ub + fc * x0.y;
            oc[i][2] = av * kup[ch * 16 + (p0 + 1) * 4 + q0]     + ub + fc * x1.x;
            oc[i][3] = av * kup[ch * 16 + (p0 + 1) * 4 + q0 + 1] + ub + fc * x1.y;
        }
        #pragma unroll
        for (int o = 0; o < 16; ++o) {
            float cbv = cbl[g * 16 + o];
            float a0 = cbv, a1 = cbv, a2 = cbv, a3 = cbv;
            #pragma unroll
            for (int i = 0; i < 16; ++i) {
                float wv = wcl[(g * 16 + o) * 16 + i];
                a0 += wv * oc[i][0]; a1 += wv * oc[i][1];
                a2 += wv * oc[i][2]; a3 += wv * oc[i][3];
            }
            xv[g * 16 + o] = fmaxf(fmaxf(a0, a1), fmaxf(a2, a3));
        }
    }

    // attn2: per-thread (one location) score + value for each head, then reduce
    int wave = t >> 6, lane = t & 63;
    #pragma unroll
    for (int nh = 0; nh < 4; ++nh) {
        float sc = 0.f;
        #pragma unroll
        for (int d = 0; d < 16; ++d) {
            int jq = nh * 16 + d, jk = 64 + nh * 16 + d;
            sc += (xv[jq / 3] * wl2[jq]) * (xv[jk / 3] * wl2[jk]);
        }
        sc *= 0.25f;
        float num[16];
        #pragma unroll
        for (int d = 0; d < 16; ++d) {
            int jv = 128 + nh * 16 + d;
            num[d] = xv[jv / 3] * wl2[jv];
        }
        float m = sc, den = 1.f;
        #pragma unroll
        for (int mask = 1; mask <= 32; mask <<= 1) {
            float mo = __shfl_xor(m, mask);
            float dn = __shfl_xor(den, mask);
            float M = fmaxf(m, mo);
            float ra = __expf(m - M), rb = __expf(mo - M);
            den = den * ra + dn * rb;
            #pragma unroll
            for (int d = 0; d < 16; ++d)
                num[d] = num[d] * ra + __shfl_xor(num[d], mask) * rb;
            m = M;
        }
        if (lane == 0) {
            red[wave][nh][0] = m; red[wave][nh][1] = den;
            #pragma unroll
            for (int d = 0; d < 16; ++d) red[wave][nh][2 + d] = num[d];
        }
    }
    __syncthreads();
    if (t < 4) {        // t = nh
        float m = -INFINITY, den = 0.f, num[16];
        #pragma unroll
        for (int d = 0; d < 16; ++d) num[d] = 0.f;
        #pragma unroll
        for (int wv = 0; wv < 4; ++wv) {
            float mo = red[wv][t][0], dn = red[wv][t][1];
            float M = fmaxf(m, mo);
            float ra = __expf(m - M), rb = __expf(mo - M);
            den = den * ra + dn * rb;
            #pragma unroll
            for (int d = 0; d < 16; ++d)
                num[d] = num[d] * ra + red[wv][t][2 + d] * rb;
            m = M;
        }
        float* p = ws + WS_P2 + ((size_t)(b * 4 + t) * 64 + hp) * 18;
        p[0] = m; p[1] = den;
        #pragma unroll
        for (int d = 0; d < 16; ++d) p[2 + d] = num[d];
    }
}

// ---------------- K7: merge attn2 partials + head math (alpha, beta) ----------------
__global__ __launch_bounds__(256) void k_tail(const float* __restrict__ bw,
                                              const float* __restrict__ bb,
                                              const float* __restrict__ cw,
                                              float* __restrict__ ws) {
    __shared__ float ohs[256], sd[256];
    int tid = threadIdx.x;
    int grp = tid >> 4;          // b*4+nh
    int j = tid & 15;
    // merge 64 partials per group: 4 serial + 16-lane butterfly
    float m = -INFINITY, den = 0.f, num[16];
    #pragma unroll
    for (int d = 0; d < 16; ++d) num[d] = 0.f;
    #pragma unroll
    for (int u = 0; u < 4; ++u) {
        const float* p = ws + WS_P2 + ((size_t)grp * 64 + j * 4 + u) * 18;
        float mo = p[0], dn = p[1];
        float M = fmaxf(m, mo);
        float ra = __expf(m - M), rb = __expf(mo - M);
        den = den * ra + dn * rb;
        #pragma unroll
        for (int d = 0; d < 16; ++d) num[d] = num[d] * ra + p[2 + d] * rb;
        m = M;
    }
    #pragma unroll
    for (int mask = 1; mask <= 8; mask <<= 1) {
        float mo = __shfl_xor(m, mask);
        float dn = __shfl_xor(den, mask);
        float M = fmaxf(m, mo);
        float ra = __expf(m - M), rb = __expf(mo - M);
        den = den * ra + dn * rb;
        #pragma unroll
        for (int d = 0; d < 16; ++d)
            num[d] = num[d] * ra + __shfl_xor(num[d], mask) * rb;
        m = M;
    }
    if (j == 0) {
        int b = grp >> 2, nh = grp & 3;
        #pragma unroll
        for (int d = 0; d < 16; ++d) ohs[b * 64 + nh * 16 + d] = num[d] / den;
    }
    __syncthreads();
    // head math (old k_head)
    int b = tid >> 6, o = tid & 63;
    float s = bb[o];
    #pragma unroll 4
    for (int c2 = 0; c2 < 64; ++c2) s += bw[o * 64 + c2] * ohs[b * 64 + c2];
    float oacc = 0.f;
    for (int u = 0; u < 4; ++u) {
        int e = tid * 4 + u;
        int g = e >> 8, oo = (e >> 4) & 15, p = e & 15;
        float ss = 0.f;
        #pragma unroll
        for (int i = 0; i < 16; ++i) ss += cw[g * 256 + oo * 16 + i] * cw[g * 256 + p * 16 + i];
        float dd = ss - ((oo == p) ? 1.0f : 0.0f);
        oacc += dd * dd;
    }
    float tot = bsum(oacc, sd, tid);
    float nd = fmaxf(fabsf(s) * 256.0f, 1e-12f);
    float t0 = ws[WS_NSTAT + 2 * b], t1 = ws[WS_NSTAT + 2 * b + 1];
    float n0 = fmaxf(ws[WS_NSTAT + 8 + 2 * b], 1e-12f);
    float n1 = fmaxf(ws[WS_NSTAT + 8 + 2 * b + 1], 1e-12f);
    float sim2 = (s / nd) * 0.5f * (t0 / n0 + t1 / n1);
    ws[WS_ALPHA + tid] = (1.0f - sim2) * s;
    if (tid == 0) ws[WS_BETA] = 2.0f - tot / 1024.0f;   // 1 + ortho
}

// ---------------- K8: final out = beta*out_clu + alpha ----------------
__global__ __launch_bounds__(256) void k_final(const float* __restrict__ x,
                                               const float* __restrict__ upk,
                                               const float* __restrict__ upb,
                                               const float* __restrict__ ws,
                                               float* __restrict__ out) {
    int idx = blockIdx.x * 256 + threadIdx.x;   // float4 index
    int r = idx >> 14;
    int rem = idx & 16383;
    int rowf = rem >> 6, c4 = rem & 63;
    int c = r & 63;
    float av = ws[WS_ATT + (size_t)r * 4096 + (rowf >> 2) * 64 + c4];
    int p = rowf & 3;
    float4 kv = ((const float4*)upk)[c * 4 + p];
    float ub = upb[c];
    float fac = ws[WS_FAC + r], al = ws[WS_ALPHA + r], be = ws[WS_BETA];
    float4 xv = ((const float4*)x)[idx];
    float4 o;
    o.x = be * (av * kv.x + ub + fac * xv.x) + al;
    o.y = be * (av * kv.y + ub + fac * xv.y) + al;
    o.z = be * (av * kv.z + ub + fac * xv.z) + al;
    o.w = be * (av * kv.w + ub + fac * xv.w) + al;
    ((float4*)out)[idx] = o;
}

extern "C" void kernel_launch(void* const* d_in, const int* in_sizes, int n_in,
                              void* d_out, int out_size, void* d_ws, size_t ws_size,
                              hipStream_t stream) {
    const float* x      = (const float*)d_in[0];
    const int*   labels = (const int*)d_in[1];
    const int*   nidx   = (const int*)d_in[2];
    const float* w1     = (const float*)d_in[3];
    const float* b1     = (const float*)d_in[4];
    const float* upk    = (const float*)d_in[5];
    const float* upb    = (const float*)d_in[6];
    const float* cw     = (const float*)d_in[7];
    const float* cb     = (const float*)d_in[8];
    const float* w2     = (const float*)d_in[9];
    const float* bw     = (const float*)d_in[10];
    const float* bb     = (const float*)d_in[11];
    float* ws  = (float*)d_ws;
    float* out = (float*)d_out;

    hipLaunchKernelGGL(k_pool4,  dim3(256),        dim3(256), 0, stream, x, nidx, ws);
    hipLaunchKernelGGL(k_gram,   dim3(2, 2, 64),   dim3(256), 0, stream, ws);
    hipLaunchKernelGGL(k_gred,   dim3(16),         dim3(256), 0, stream, ws);
    hipLaunchKernelGGL(k_attn1,  dim3(256),        dim3(256), 0, stream, labels, w1, b1, ws);
    hipLaunchKernelGGL(k_attmm,  dim3(64, 4),      dim3(256), 0, stream, ws);
    hipLaunchKernelGGL(k_sim,    dim3(256),        dim3(256), 0, stream, x, nidx, upk, upb, ws);
    hipLaunchKernelGGL(k_cluat,  dim3(64, 4),      dim3(256), 0, stream, x, upk, upb, cw, cb, w2, ws);
    hipLaunchKernelGGL(k_tail,   dim3(1),          dim3(256), 0, stream, bw, bb, cw, ws);
    hipLaunchKernelGGL(k_final,  dim3(16384),      dim3(256), 0, stream, x, upk, upb, ws, out);
}

// Round 5
// 112.158 us; speedup vs baseline: 1.9354x; 1.9354x over previous
//
#include <hip/hip_runtime.h>
#include <math.h>

// ---------------- workspace layout (float offsets) ----------------
#define WS_XD     0u          // 256*4096          pooled-4 x, row-major
#define WS_S      1048576u    // 256               row sums of xd
#define WS_GPART  1048832u    // 64*128*128        Gram partials (K-split)
#define WS_G      2097408u    // 128*128           Gram region rows[0,128) cols rb-80
#define WS_COEF   2113792u    // 256*96            attn@v coefficients (xd rows 170..255)
#define WS_CONST  2138368u    // 256
#define WS_ATT    2138624u    // 256*4096          attention-1 output (B,C,64,64)
#define WS_FAC    3187200u    // 256               2 - sim
#define WS_XDS    3187456u    // 4*64*128*128      pooled-2 group-conv output
#define WS_ALPHA  7382016u    // 256
#define WS_BETA   7382272u    // 1
#define WS_NSTAT  7382273u    // 16 (T[8], nrm[8])
#define WS_P2     7382304u    // 16*32*18          attn2 softmax partials

__device__ __forceinline__ float bsum(float v, float* sd, int tid) {
    sd[tid] = v; __syncthreads();
    for (int off = 128; off > 0; off >>= 1) {
        if (tid < off) sd[tid] += sd[tid + off];
        __syncthreads();
    }
    float r = sd[0]; __syncthreads(); return r;
}
__device__ __forceinline__ float bmax(float v, float* sd, int tid) {
    sd[tid] = v; __syncthreads();
    for (int off = 128; off > 0; off >>= 1) {
        if (tid < off) sd[tid] = fmaxf(sd[tid], sd[tid + off]);
        __syncthreads();
    }
    float r = sd[0]; __syncthreads(); return r;
}

// ---------------- K1: 4x4 maxpool + row sums (+ noise row stats folded in) ----------------
__global__ __launch_bounds__(256) void k_pool4(const float* __restrict__ x,
                                               const int* __restrict__ nidx,
                                               float* __restrict__ ws) {
    __shared__ float sd[256];
    int r = blockIdx.x, tid = threadIdx.x;
    const float4* xr = (const float4*)x + (size_t)r * 16384;
    float* xd = ws + WS_XD + (size_t)r * 4096;
    float sum = 0.f, s = 0.f, ss = 0.f;
    for (int it = 0; it < 16; ++it) {
        int o = it * 256 + tid;
        int h = o >> 6, w = o & 63;
        float m = -INFINITY;
        #pragma unroll
        for (int p = 0; p < 4; ++p) {
            float4 v = xr[(4 * h + p) * 64 + w];
            m = fmaxf(m, fmaxf(fmaxf(v.x, v.y), fmaxf(v.z, v.w)));
            s  += v.x + v.y + v.z + v.w;
            ss += v.x*v.x + v.y*v.y + v.z*v.z + v.w*v.w;
        }
        xd[o] = m; sum += m;
    }
    float st = bsum(sum, sd, tid);
    if (tid == 0) ws[WS_S + r] = st;
    // noise stats (uniform branch: r is block-uniform)
    bool isn = false;
    #pragma unroll
    for (int n = 0; n < 8; ++n) isn = isn || (nidx[n] == r);
    if (isn) {
        float ts = bsum(s, sd, tid);
        float tss = bsum(ss, sd, tid);
        if (tid == 0) {
            for (int n = 0; n < 8; ++n)
                if (nidx[n] == r) { ws[WS_NSTAT + n] = ts; ws[WS_NSTAT + 8 + n] = sqrtf(tss); }
        }
    }
}

// ---------------- K2: Gram partials: rows[0,128) x cols[80,208), K-split 64 ----------------
__global__ __launch_bounds__(256) void k_gram(float* __restrict__ ws) {
    __shared__ __align__(16) float As[64][68];
    __shared__ __align__(16) float Bs[64][68];
    int tid = threadIdx.x, tx = tid & 15, ty = tid >> 4;
    int ra0 = blockIdx.y * 64, rb0 = 80 + blockIdx.x * 64, k0 = blockIdx.z * 64;
    const float4* xd4 = (const float4*)(ws + WS_XD);
    #pragma unroll
    for (int q = 0; q < 4; ++q) {
        int idx = q * 256 + tid;
        int row = idx >> 4, cf = idx & 15;
        float4 a = xd4[(size_t)(ra0 + row) * 1024 + (k0 >> 2) + cf];
        As[cf*4+0][row] = a.x; As[cf*4+1][row] = a.y; As[cf*4+2][row] = a.z; As[cf*4+3][row] = a.w;
        float4 b = xd4[(size_t)(rb0 + row) * 1024 + (k0 >> 2) + cf];
        Bs[cf*4+0][row] = b.x; Bs[cf*4+1][row] = b.y; Bs[cf*4+2][row] = b.z; Bs[cf*4+3][row] = b.w;
    }
    __syncthreads();
    float acc[4][4] = {};
    #pragma unroll 4
    for (int kk = 0; kk < 64; ++kk) {
        float4 a = *(const float4*)&As[kk][ty * 4];
        float4 b = *(const float4*)&Bs[kk][tx * 4];
        acc[0][0] += a.x*b.x; acc[0][1] += a.x*b.y; acc[0][2] += a.x*b.z; acc[0][3] += a.x*b.w;
        acc[1][0] += a.y*b.x; acc[1][1] += a.y*b.y; acc[1][2] += a.y*b.z; acc[1][3] += a.y*b.w;
        acc[2][0] += a.z*b.x; acc[2][1] += a.z*b.y; acc[2][2] += a.z*b.z; acc[2][3] += a.z*b.w;
        acc[3][0] += a.w*b.x; acc[3][1] += a.w*b.y; acc[3][2] += a.w*b.z; acc[3][3] += a.w*b.w;
    }
    float* gp = ws + WS_GPART + (size_t)blockIdx.z * 16384;
    #pragma unroll
    for (int i = 0; i < 4; ++i) {
        float4 o = make_float4(acc[i][0], acc[i][1], acc[i][2], acc[i][3]);
        *(float4*)&gp[(size_t)(ra0 + ty * 4 + i) * 128 + blockIdx.x * 64 + tx * 4] = o;
    }
}

// ---------------- K2b: reduce Gram partials ----------------
__global__ __launch_bounds__(256) void k_gred(float* __restrict__ ws) {
    int t = blockIdx.x * 256 + threadIdx.x;   // float4 index, 4096 total
    const float4* gp = (const float4*)(ws + WS_GPART);
    float4 s = make_float4(0.f, 0.f, 0.f, 0.f);
    for (int p = 0; p < 64; ++p) {
        float4 v = gp[(size_t)p * 4096 + t];
        s.x += v.x; s.y += v.y; s.z += v.z; s.w += v.w;
    }
    ((float4*)(ws + WS_G))[t] = s;
}

// ---------------- K3: masked softmax row -> coef/const ----------------
__global__ __launch_bounds__(256) void k_attn1(const int* __restrict__ labels,
                                               const float* __restrict__ w1,
                                               const float* __restrict__ b1,
                                               float* __restrict__ ws) {
    __shared__ float sd[256];
    __shared__ float attn_s[256];
    int i = blockIdx.x, tid = threadIdx.x;
    int labi = labels[i];
    bool validi = (labi != -1);
    int bi = (i >= 192) ? 1 : 0;
    int ji = i - bi * 192;
    int rq = bi * 64 + ji / 3;
    float wq = w1[ji], bq = b1[ji];
    int gk = 256 + tid;
    int bk = (gk >= 384) ? 2 : 1;
    int jk = gk - bk * 192;
    int rk = bk * 64 + jk / 3;
    float wk = w1[jk], bbk = b1[jk];
    int labj = labels[tid];
    bool allowed = validi && (labj == labi) && (labj != -1);
    float score = wq * wk * ws[WS_G + rq * 128 + (rk - 80)]
                + wq * bbk * ws[WS_S + rq]
                + wk * bq  * ws[WS_S + rk]
                + 4096.0f * bq * bbk;
    float sc = allowed ? score : -1e30f;
    float m = bmax(sc, sd, tid);
    float e = __expf(sc - m);
    float Z = bsum(e, sd, tid);
    float attn = validi ? (e / Z) : 0.0f;
    attn_s[tid] = attn;
    int gv = 512 + tid;
    int bv = (gv >= 576) ? 3 : 2;
    int jv = gv - bv * 192;
    float csum = bsum(attn * b1[jv], sd, tid);   // barrier also publishes attn_s
    if (tid < 96) {
        float s = 0.0f;
        if (tid < 86) {
            int rv = 170 + tid;
            int lo, hi, jadd;
            if (rv < 192) { int c = rv - 128; lo = 3 * c; if (lo < 128) lo = 128; hi = 3 * c + 2; jadd = -128; }
            else          { int c = rv - 192; lo = 3 * c; hi = 3 * c + 2; jadd = 64; }
            for (int jj = lo; jj <= hi; ++jj) s += attn_s[jj + jadd] * w1[jj];
        }
        ws[WS_COEF + i * 96 + tid] = s;
    }
    if (tid == 0) ws[WS_CONST + i] = csum;
}

// ---------------- K4: att = coef @ xd[170:256] + const ----------------
__global__ __launch_bounds__(256) void k_attmm(float* __restrict__ ws) {
    __shared__ __align__(16) float As[96][68];
    __shared__ __align__(16) float Bs[96][64];
    int tid = threadIdx.x, tx = tid & 15, ty = tid >> 4;
    int col0 = blockIdx.x * 64, row0 = blockIdx.y * 64;
    const float4* cf4 = (const float4*)(ws + WS_COEF);
    const float4* xd4 = (const float4*)(ws + WS_XD);
    #pragma unroll
    for (int q = 0; q < 6; ++q) {
        int f = q * 256 + tid;
        {
            int row = f / 24, c24 = f - row * 24;
            float4 v = cf4[(size_t)(row0 + row) * 24 + c24];
            As[c24*4+0][row] = v.x; As[c24*4+1][row] = v.y; As[c24*4+2][row] = v.z; As[c24*4+3][row] = v.w;
        }
        {
            int row = f >> 4, c16 = f & 15;
            float4 v = make_float4(0.f, 0.f, 0.f, 0.f);
            if (row < 86) v = xd4[(size_t)(170 + row) * 1024 + (col0 >> 2) + c16];
            *(float4*)&Bs[row][c16 * 4] = v;
        }
    }
    __syncthreads();
    float acc[4][4] = {};
    #pragma unroll 4
    for (int kk = 0; kk < 96; ++kk) {
        float4 a = *(const float4*)&As[kk][ty * 4];
        float4 b = *(const float4*)&Bs[kk][tx * 4];
        acc[0][0] += a.x*b.x; acc[0][1] += a.x*b.y; acc[0][2] += a.x*b.z; acc[0][3] += a.x*b.w;
        acc[1][0] += a.y*b.x; acc[1][1] += a.y*b.y; acc[1][2] += a.y*b.z; acc[1][3] += a.y*b.w;
        acc[2][0] += a.z*b.x; acc[2][1] += a.z*b.y; acc[2][2] += a.z*b.z; acc[2][3] += a.z*b.w;
        acc[3][0] += a.w*b.x; acc[3][1] += a.w*b.y; acc[3][2] += a.w*b.z; acc[3][3] += a.w*b.w;
    }
    float* att = ws + WS_ATT;
    #pragma unroll
    for (int i = 0; i < 4; ++i) {
        int row = row0 + ty * 4 + i;
        float cv = ws[WS_CONST + row];
        float4 o = make_float4(acc[i][0] + cv, acc[i][1] + cv, acc[i][2] + cv, acc[i][3] + cv);
        *(float4*)&att[(size_t)row * 4096 + col0 + tx * 4] = o;
    }
}

// ---------------- K5: sim(b,c) -> fac = 2 - sim ----------------
__global__ __launch_bounds__(256) void k_sim(const float* __restrict__ x,
                                             const int* __restrict__ nidx,
                                             const float* __restrict__ upk,
                                             const float* __restrict__ upb,
                                             float* __restrict__ ws) {
    __shared__ float sd[256];
    int r = blockIdx.x, tid = threadIdx.x;
    int b = r >> 6, c = r & 63;
    const float* att = ws + WS_ATT + (size_t)r * 4096;
    const float4* xn0 = (const float4*)x + (size_t)nidx[2 * b] * 16384;
    const float4* xn1 = (const float4*)x + (size_t)nidx[2 * b + 1] * 16384;
    const float4* k4p = (const float4*)upk + c * 4;
    float ub = upb[c];
    float4 kk0 = k4p[0], kk1 = k4p[1], kk2 = k4p[2], kk3 = k4p[3];
    float s2 = 0.f, d0 = 0.f, d1 = 0.f;
    for (int it = 0; it < 64; ++it) {
        int f = it * 256 + tid;
        int rowf = f >> 6, c4 = f & 63;
        float av = att[(rowf >> 2) * 64 + c4];
        int p = rowf & 3;
        float4 kv = (p == 0) ? kk0 : ((p == 1) ? kk1 : ((p == 2) ? kk2 : kk3));
        float4 a0 = xn0[f], a1 = xn1[f];
        float u;
        u = av * kv.x + ub; s2 += u * u; d0 += u * a0.x; d1 += u * a1.x;
        u = av * kv.y + ub; s2 += u * u; d0 += u * a0.y; d1 += u * a1.y;
        u = av * kv.z + ub; s2 += u * u; d0 += u * a0.z; d1 += u * a1.z;
        u = av * kv.w + ub; s2 += u * u; d0 += u * a0.w; d1 += u * a1.w;
    }
    s2 = bsum(s2, sd, tid);
    d0 = bsum(d0, sd, tid);
    d1 = bsum(d1, sd, tid);
    if (tid == 0) {
        float nup = fmaxf(sqrtf(s2), 1e-12f);
        float n0 = fmaxf(ws[WS_NSTAT + 8 + 2 * b], 1e-12f);
        float n1 = fmaxf(ws[WS_NSTAT + 8 + 2 * b + 1], 1e-12f);
        float sim = 0.5f * (d0 / (nup * n0) + d1 / (nup * n1));
        ws[WS_FAC + r] = 2.0f - sim;
    }
}

// ---------------- K6: fused out_clu -> group conv -> maxpool2 -> x_ds ----------------
__global__ __launch_bounds__(256) void k_cluds(const float* __restrict__ x,
                                               const float* __restrict__ upk,
                                               const float* __restrict__ upb,
                                               const float* __restrict__ cw,
                                               const float* __restrict__ cb,
                                               float* __restrict__ ws) {
    __shared__ float wcl[256];   // clu_w[g][o][i]
    __shared__ float kup[256];   // up_k for channels g*16..g*16+15
    __shared__ float cbl[16], ubl[16], fcl[16];
    int h2 = blockIdx.x, g = blockIdx.y, b = blockIdx.z;
    int t = threadIdx.x;
    wcl[t] = cw[g * 256 + t];
    kup[t] = upk[g * 256 + t];
    if (t < 16) {
        cbl[t] = cb[g * 16 + t];
        ubl[t] = upb[g * 16 + t];
        fcl[t] = ws[WS_FAC + b * 64 + g * 16 + t];
    }
    __syncthreads();
    int r0 = 2 * h2;
    int h_att = h2 >> 1, p0 = r0 & 3;
    int wa = t >> 2, q = t & 3;
    float oc0[16], oc1[16];
    const float* attb = ws + WS_ATT;
    #pragma unroll
    for (int i = 0; i < 16; ++i) {
        int cch = g * 16 + i;
        float av = attb[(size_t)(b * 64 + cch) * 4096 + h_att * 64 + wa];
        float u0 = av * kup[i * 16 + p0 * 4 + q] + ubl[i];
        float u1 = av * kup[i * 16 + (p0 + 1) * 4 + q] + ubl[i];
        const float* xrow = x + (size_t)(b * 64 + cch) * 65536;
        float x0 = xrow[r0 * 256 + t];
        float x1 = xrow[(r0 + 1) * 256 + t];
        oc0[i] = u0 + fcl[i] * x0;
        oc1[i] = u1 + fcl[i] * x1;
    }
    float* xds = ws + WS_XDS;
    #pragma unroll
    for (int o = 0; o < 16; ++o) {
        float a0 = cbl[o], a1 = cbl[o];
        #pragma unroll
        for (int i = 0; i < 16; ++i) {
            a0 += wcl[o * 16 + i] * oc0[i];
            a1 += wcl[o * 16 + i] * oc1[i];
        }
        float m = fmaxf(a0, a1);
        m = fmaxf(m, __shfl_xor(m, 1));
        if ((t & 1) == 0)
            xds[(size_t)((b * 64 + g * 16 + o) * 128 + h2) * 128 + (t >> 1)] = m;
    }
}

// ---------------- K7a: head attention partials (32 chunks per (b,nh)) ----------------
__global__ __launch_bounds__(256) void k_attn2a(const float* __restrict__ w2,
                                                float* __restrict__ ws) {
    __shared__ float ms[256], dsh[256];
    __shared__ float ns[256][16];
    int chunk = blockIdx.x, nh = blockIdx.y, b = blockIdx.z, tid = threadIdx.x;
    const float* X = ws + WS_XDS + (size_t)b * 1048576;
    float wqd[16], wkd[16], wvd[16];
    int oq[16], ok[16], ovo[16];
    #pragma unroll
    for (int d = 0; d < 16; ++d) {
        int jq = nh * 16 + d, jk = 64 + nh * 16 + d, jv = 128 + nh * 16 + d;
        wqd[d] = w2[jq]; wkd[d] = w2[jk]; wvd[d] = w2[jv];
        oq[d] = (jq / 3) * 16384; ok[d] = (jk / 3) * 16384; ovo[d] = (jv / 3) * 16384;
    }
    float m = -INFINITY, den = 0.f, num[16];
    #pragma unroll
    for (int d = 0; d < 16; ++d) num[d] = 0.f;
    #pragma unroll
    for (int e = 0; e < 2; ++e) {
        int l = chunk * 512 + e * 256 + tid;
        float sc = 0.f;
        #pragma unroll
        for (int d = 0; d < 16; ++d) sc += (X[oq[d] + l] * wqd[d]) * (X[ok[d] + l] * wkd[d]);
        sc *= 0.25f;
        float nm = fmaxf(m, sc);
        float rr = __expf(m - nm), ee = __expf(sc - nm);
        den = den * rr + ee;
        #pragma unroll
        for (int d = 0; d < 16; ++d) num[d] = num[d] * rr + ee * (X[ovo[d] + l] * wvd[d]);
        m = nm;
    }
    ms[tid] = m; dsh[tid] = den;
    #pragma unroll
    for (int d = 0; d < 16; ++d) ns[tid][d] = num[d];
    __syncthreads();
    for (int off = 128; off > 0; off >>= 1) {
        if (tid < off) {
            float ma = ms[tid], mb = ms[tid + off];
            float M = fmaxf(ma, mb);
            float ra = __expf(ma - M), rb = __expf(mb - M);
            dsh[tid] = dsh[tid] * ra + dsh[tid + off] * rb;
            #pragma unroll
            for (int d = 0; d < 16; ++d)
                ns[tid][d] = ns[tid][d] * ra + ns[tid + off][d] * rb;
            ms[tid] = M;
        }
        __syncthreads();
    }
    if (tid == 0) {
        float* p = ws + WS_P2 + ((size_t)(b * 4 + nh) * 32 + chunk) * 18;
        p[0] = ms[0]; p[1] = dsh[0];
        #pragma unroll
        for (int d = 0; d < 16; ++d) p[2 + d] = ns[0][d];
    }
}

// ---------------- K7b: merge attn2 partials + head math (alpha, beta) ----------------
__global__ __launch_bounds__(256) void k_tail(const float* __restrict__ bw,
                                              const float* __restrict__ bb,
                                              const float* __restrict__ cw,
                                              float* __restrict__ ws) {
    __shared__ float ohs[256], sd[256];
    int tid = threadIdx.x;
    int grp = tid >> 4;          // b*4+nh  (16 groups)
    int j = tid & 15;
    // merge 32 partials per group: 2 serial + 16-lane butterfly
    float m = -INFINITY, den = 0.f, num[16];
    #pragma unroll
    for (int d = 0; d < 16; ++d) num[d] = 0.f;
    #pragma unroll
    for (int u = 0; u < 2; ++u) {
        const float* p = ws + WS_P2 + ((size_t)grp * 32 + j * 2 + u) * 18;
        float mo = p[0], dn = p[1];
        float M = fmaxf(m, mo);
        float ra = __expf(m - M), rb = __expf(mo - M);
        den = den * ra + dn * rb;
        #pragma unroll
        for (int d = 0; d < 16; ++d) num[d] = num[d] * ra + p[2 + d] * rb;
        m = M;
    }
    #pragma unroll
    for (int mask = 1; mask <= 8; mask <<= 1) {
        float mo = __shfl_xor(m, mask);
        float dn = __shfl_xor(den, mask);
        float M = fmaxf(m, mo);
        float ra = __expf(m - M), rb = __expf(mo - M);
        den = den * ra + dn * rb;
        #pragma unroll
        for (int d = 0; d < 16; ++d)
            num[d] = num[d] * ra + __shfl_xor(num[d], mask) * rb;
        m = M;
    }
    if (j == 0) {
        int b = grp >> 2, nh = grp & 3;
        #pragma unroll
        for (int d = 0; d < 16; ++d) ohs[b * 64 + nh * 16 + d] = num[d] / den;
    }
    __syncthreads();
    // head math
    int b = tid >> 6, o = tid & 63;
    float s = bb[o];
    #pragma unroll 4
    for (int c2 = 0; c2 < 64; ++c2) s += bw[o * 64 + c2] * ohs[b * 64 + c2];
    float oacc = 0.f;
    for (int u = 0; u < 4; ++u) {
        int e = tid * 4 + u;
        int g = e >> 8, oo = (e >> 4) & 15, p = e & 15;
        float ss = 0.f;
        #pragma unroll
        for (int i = 0; i < 16; ++i) ss += cw[g * 256 + oo * 16 + i] * cw[g * 256 + p * 16 + i];
        float dd = ss - ((oo == p) ? 1.0f : 0.0f);
        oacc += dd * dd;
    }
    float tot = bsum(oacc, sd, tid);
    float nd = fmaxf(fabsf(s) * 256.0f, 1e-12f);
    float t0 = ws[WS_NSTAT + 2 * b], t1 = ws[WS_NSTAT + 2 * b + 1];
    float n0 = fmaxf(ws[WS_NSTAT + 8 + 2 * b], 1e-12f);
    float n1 = fmaxf(ws[WS_NSTAT + 8 + 2 * b + 1], 1e-12f);
    float sim2 = (s / nd) * 0.5f * (t0 / n0 + t1 / n1);
    ws[WS_ALPHA + tid] = (1.0f - sim2) * s;
    if (tid == 0) ws[WS_BETA] = 2.0f - tot / 1024.0f;   // 1 + ortho
}

// ---------------- K8: final out = beta*out_clu + alpha ----------------
__global__ __launch_bounds__(256) void k_final(const float* __restrict__ x,
                                               const float* __restrict__ upk,
                                               const float* __restrict__ upb,
                                               const float* __restrict__ ws,
                                               float* __restrict__ out) {
    int idx = blockIdx.x * 256 + threadIdx.x;   // float4 index
    int r = idx >> 14;
    int rem = idx & 16383;
    int rowf = rem >> 6, c4 = rem & 63;
    int c = r & 63;
    float av = ws[WS_ATT + (size_t)r * 4096 + (rowf >> 2) * 64 + c4];
    int p = rowf & 3;
    float4 kv = ((const float4*)upk)[c * 4 + p];
    float ub = upb[c];
    float fac = ws[WS_FAC + r], al = ws[WS_ALPHA + r], be = ws[WS_BETA];
    float4 xv = ((const float4*)x)[idx];
    float4 o;
    o.x = be * (av * kv.x + ub + fac * xv.x) + al;
    o.y = be * (av * kv.y + ub + fac * xv.y) + al;
    o.z = be * (av * kv.z + ub + fac * xv.z) + al;
    o.w = be * (av * kv.w + ub + fac * xv.w) + al;
    ((float4*)out)[idx] = o;
}

extern "C" void kernel_launch(void* const* d_in, const int* in_sizes, int n_in,
                              void* d_out, int out_size, void* d_ws, size_t ws_size,
                              hipStream_t stream) {
    const float* x      = (const float*)d_in[0];
    const int*   labels = (const int*)d_in[1];
    const int*   nidx   = (const int*)d_in[2];
    const float* w1     = (const float*)d_in[3];
    const float* b1     = (const float*)d_in[4];
    const float* upk    = (const float*)d_in[5];
    const float* upb    = (const float*)d_in[6];
    const float* cw     = (const float*)d_in[7];
    const float* cb     = (const float*)d_in[8];
    const float* w2     = (const float*)d_in[9];
    const float* bw     = (const float*)d_in[10];
    const float* bb     = (const float*)d_in[11];
    float* ws  = (float*)d_ws;
    float* out = (float*)d_out;

    hipLaunchKernelGGL(k_pool4,  dim3(256),        dim3(256), 0, stream, x, nidx, ws);
    hipLaunchKernelGGL(k_gram,   dim3(2, 2, 64),   dim3(256), 0, stream, ws);
    hipLaunchKernelGGL(k_gred,   dim3(16),         dim3(256), 0, stream, ws);
    hipLaunchKernelGGL(k_attn1,  dim3(256),        dim3(256), 0, stream, labels, w1, b1, ws);
    hipLaunchKernelGGL(k_attmm,  dim3(64, 4),      dim3(256), 0, stream, ws);
    hipLaunchKernelGGL(k_sim,    dim3(256),        dim3(256), 0, stream, x, nidx, upk, upb, ws);
    hipLaunchKernelGGL(k_cluds,  dim3(128, 4, 4),  dim3(256), 0, stream, x, upk, upb, cw, cb, ws);
    hipLaunchKernelGGL(k_attn2a, dim3(32, 4, 4),   dim3(256), 0, stream, w2, ws);
    hipLaunchKernelGGL(k_tail,   dim3(1),          dim3(256), 0, stream, bw, bb, cw, ws);
    hipLaunchKernelGGL(k_final,  dim3(16384),      dim3(256), 0, stream, x, upk, upb, ws, out);
}

// Round 6
// 107.933 us; speedup vs baseline: 2.0111x; 1.0391x over previous
//
#include <hip/hip_runtime.h>
#include <math.h>

// ---------------- workspace layout (float offsets) ----------------
#define WS_XD     0u          // 256*4096          pooled-4 x, row-major
#define WS_S      1048576u    // 256               row sums of xd
#define WS_GPART  1048832u    // 64*128*128        Gram partials (K-split)
#define WS_COEF   2113792u    // 256*96            attn@v coefficients (xd rows 170..255)
#define WS_CONST  2138368u    // 256
#define WS_ATT    2138624u    // 256*4096          attention-1 output (B,C,64,64)
#define WS_FAC    3187200u    // 256               2 - sim
#define WS_XDS    3187456u    // 4*64*128*128      pooled-2 group-conv output
#define WS_ALPHA  7382016u    // 256
#define WS_BETA   7382272u    // 1
#define WS_NSTAT  7382273u    // 16 (T[8], nrm[8])
#define WS_P2     7382304u    // 16*16*18          attn2 softmax partials

__device__ __forceinline__ float bsum(float v, float* sd, int tid) {
    sd[tid] = v; __syncthreads();
    for (int off = 128; off > 0; off >>= 1) {
        if (tid < off) sd[tid] += sd[tid + off];
        __syncthreads();
    }
    float r = sd[0]; __syncthreads(); return r;
}
__device__ __forceinline__ float bmax(float v, float* sd, int tid) {
    sd[tid] = v; __syncthreads();
    for (int off = 128; off > 0; off >>= 1) {
        if (tid < off) sd[tid] = fmaxf(sd[tid], sd[tid + off]);
        __syncthreads();
    }
    float r = sd[0]; __syncthreads(); return r;
}

// ---------------- K1: 4x4 maxpool + row sums (+ noise row stats folded in) ----------------
__global__ __launch_bounds__(256) void k_pool4(const float* __restrict__ x,
                                               const int* __restrict__ nidx,
                                               float* __restrict__ ws) {
    __shared__ float sd[256];
    int r = blockIdx.x, tid = threadIdx.x;
    const float4* xr = (const float4*)x + (size_t)r * 16384;
    float* xd = ws + WS_XD + (size_t)r * 4096;
    float sum = 0.f, s = 0.f, ss = 0.f;
    for (int it = 0; it < 16; ++it) {
        int o = it * 256 + tid;
        int h = o >> 6, w = o & 63;
        float m = -INFINITY;
        #pragma unroll
        for (int p = 0; p < 4; ++p) {
            float4 v = xr[(4 * h + p) * 64 + w];
            m = fmaxf(m, fmaxf(fmaxf(v.x, v.y), fmaxf(v.z, v.w)));
            s  += v.x + v.y + v.z + v.w;
            ss += v.x*v.x + v.y*v.y + v.z*v.z + v.w*v.w;
        }
        xd[o] = m; sum += m;
    }
    float st = bsum(sum, sd, tid);
    if (tid == 0) ws[WS_S + r] = st;
    bool isn = false;
    #pragma unroll
    for (int n = 0; n < 8; ++n) isn = isn || (nidx[n] == r);
    if (isn) {
        float ts = bsum(s, sd, tid);
        float tss = bsum(ss, sd, tid);
        if (tid == 0) {
            for (int n = 0; n < 8; ++n)
                if (nidx[n] == r) { ws[WS_NSTAT + n] = ts; ws[WS_NSTAT + 8 + n] = sqrtf(tss); }
        }
    }
}

// ---------------- K2: Gram partials: rows[0,128) x cols[80,208), K-split 64 ----------------
__global__ __launch_bounds__(256) void k_gram(float* __restrict__ ws) {
    __shared__ __align__(16) float As[64][68];
    __shared__ __align__(16) float Bs[64][68];
    int tid = threadIdx.x, tx = tid & 15, ty = tid >> 4;
    int ra0 = blockIdx.y * 64, rb0 = 80 + blockIdx.x * 64, k0 = blockIdx.z * 64;
    const float4* xd4 = (const float4*)(ws + WS_XD);
    #pragma unroll
    for (int q = 0; q < 4; ++q) {
        int idx = q * 256 + tid;
        int row = idx >> 4, cf = idx & 15;
        float4 a = xd4[(size_t)(ra0 + row) * 1024 + (k0 >> 2) + cf];
        As[cf*4+0][row] = a.x; As[cf*4+1][row] = a.y; As[cf*4+2][row] = a.z; As[cf*4+3][row] = a.w;
        float4 b = xd4[(size_t)(rb0 + row) * 1024 + (k0 >> 2) + cf];
        Bs[cf*4+0][row] = b.x; Bs[cf*4+1][row] = b.y; Bs[cf*4+2][row] = b.z; Bs[cf*4+3][row] = b.w;
    }
    __syncthreads();
    float acc[4][4] = {};
    #pragma unroll 4
    for (int kk = 0; kk < 64; ++kk) {
        float4 a = *(const float4*)&As[kk][ty * 4];
        float4 b = *(const float4*)&Bs[kk][tx * 4];
        acc[0][0] += a.x*b.x; acc[0][1] += a.x*b.y; acc[0][2] += a.x*b.z; acc[0][3] += a.x*b.w;
        acc[1][0] += a.y*b.x; acc[1][1] += a.y*b.y; acc[1][2] += a.y*b.z; acc[1][3] += a.y*b.w;
        acc[2][0] += a.z*b.x; acc[2][1] += a.z*b.y; acc[2][2] += a.z*b.z; acc[2][3] += a.z*b.w;
        acc[3][0] += a.w*b.x; acc[3][1] += a.w*b.y; acc[3][2] += a.w*b.z; acc[3][3] += a.w*b.w;
    }
    float* gp = ws + WS_GPART + (size_t)blockIdx.z * 16384;
    #pragma unroll
    for (int i = 0; i < 4; ++i) {
        float4 o = make_float4(acc[i][0], acc[i][1], acc[i][2], acc[i][3]);
        *(float4*)&gp[(size_t)(ra0 + ty * 4 + i) * 128 + blockIdx.x * 64 + tx * 4] = o;
    }
}

// ---------------- K3: (gred row-reduce) + masked softmax row -> coef/const ----------------
__global__ __launch_bounds__(256) void k_attn1(const int* __restrict__ labels,
                                               const float* __restrict__ w1,
                                               const float* __restrict__ b1,
                                               float* __restrict__ ws) {
    __shared__ float sd[256];
    __shared__ float attn_s[256];
    __shared__ float grow[128];
    int i = blockIdx.x, tid = threadIdx.x;
    int labi = labels[i];
    bool validi = (labi != -1);
    int bi = (i >= 192) ? 1 : 0;
    int ji = i - bi * 192;
    int rq = bi * 64 + ji / 3;
    // reduce Gram partials for row rq only
    if (tid < 128) {
        const float* gp = ws + WS_GPART + (size_t)rq * 128 + tid;
        float acc = 0.f;
        #pragma unroll 8
        for (int p = 0; p < 64; ++p) acc += gp[(size_t)p * 16384];
        grow[tid] = acc;
    }
    __syncthreads();
    float wq = w1[ji], bq = b1[ji];
    int gk = 256 + tid;
    int bk = (gk >= 384) ? 2 : 1;
    int jk = gk - bk * 192;
    int rk = bk * 64 + jk / 3;
    float wk = w1[jk], bbk = b1[jk];
    int labj = labels[tid];
    bool allowed = validi && (labj == labi) && (labj != -1);
    float score = wq * wk * grow[rk - 80]
                + wq * bbk * ws[WS_S + rq]
                + wk * bq  * ws[WS_S + rk]
                + 4096.0f * bq * bbk;
    float sc = allowed ? score : -1e30f;
    float m = bmax(sc, sd, tid);
    float e = __expf(sc - m);
    float Z = bsum(e, sd, tid);
    float attn = validi ? (e / Z) : 0.0f;
    attn_s[tid] = attn;
    int gv = 512 + tid;
    int bv = (gv >= 576) ? 3 : 2;
    int jv = gv - bv * 192;
    float csum = bsum(attn * b1[jv], sd, tid);   // barrier also publishes attn_s
    if (tid < 96) {
        float s = 0.0f;
        if (tid < 86) {
            int rv = 170 + tid;
            int lo, hi, jadd;
            if (rv < 192) { int c = rv - 128; lo = 3 * c; if (lo < 128) lo = 128; hi = 3 * c + 2; jadd = -128; }
            else          { int c = rv - 192; lo = 3 * c; hi = 3 * c + 2; jadd = 64; }
            for (int jj = lo; jj <= hi; ++jj) s += attn_s[jj + jadd] * w1[jj];
        }
        ws[WS_COEF + i * 96 + tid] = s;
    }
    if (tid == 0) ws[WS_CONST + i] = csum;
}

// ---------------- K4: att = coef @ xd[170:256] + const ----------------
__global__ __launch_bounds__(256) void k_attmm(float* __restrict__ ws) {
    __shared__ __align__(16) float As[96][68];
    __shared__ __align__(16) float Bs[96][64];
    int tid = threadIdx.x, tx = tid & 15, ty = tid >> 4;
    int col0 = blockIdx.x * 64, row0 = blockIdx.y * 64;
    const float4* cf4 = (const float4*)(ws + WS_COEF);
    const float4* xd4 = (const float4*)(ws + WS_XD);
    #pragma unroll
    for (int q = 0; q < 6; ++q) {
        int f = q * 256 + tid;
        {
            int row = f / 24, c24 = f - row * 24;
            float4 v = cf4[(size_t)(row0 + row) * 24 + c24];
            As[c24*4+0][row] = v.x; As[c24*4+1][row] = v.y; As[c24*4+2][row] = v.z; As[c24*4+3][row] = v.w;
        }
        {
            int row = f >> 4, c16 = f & 15;
            float4 v = make_float4(0.f, 0.f, 0.f, 0.f);
            if (row < 86) v = xd4[(size_t)(170 + row) * 1024 + (col0 >> 2) + c16];
            *(float4*)&Bs[row][c16 * 4] = v;
        }
    }
    __syncthreads();
    float acc[4][4] = {};
    #pragma unroll 4
    for (int kk = 0; kk < 96; ++kk) {
        float4 a = *(const float4*)&As[kk][ty * 4];
        float4 b = *(const float4*)&Bs[kk][tx * 4];
        acc[0][0] += a.x*b.x; acc[0][1] += a.x*b.y; acc[0][2] += a.x*b.z; acc[0][3] += a.x*b.w;
        acc[1][0] += a.y*b.x; acc[1][1] += a.y*b.y; acc[1][2] += a.y*b.z; acc[1][3] += a.y*b.w;
        acc[2][0] += a.z*b.x; acc[2][1] += a.z*b.y; acc[2][2] += a.z*b.z; acc[2][3] += a.z*b.w;
        acc[3][0] += a.w*b.x; acc[3][1] += a.w*b.y; acc[3][2] += a.w*b.z; acc[3][3] += a.w*b.w;
    }
    float* att = ws + WS_ATT;
    #pragma unroll
    for (int i = 0; i < 4; ++i) {
        int row = row0 + ty * 4 + i;
        float cv = ws[WS_CONST + row];
        float4 o = make_float4(acc[i][0] + cv, acc[i][1] + cv, acc[i][2] + cv, acc[i][3] + cv);
        *(float4*)&att[(size_t)row * 4096 + col0 + tx * 4] = o;
    }
}

// ---------------- K5: sim(b,c) -> fac = 2 - sim ----------------
__global__ __launch_bounds__(256) void k_sim(const float* __restrict__ x,
                                             const int* __restrict__ nidx,
                                             const float* __restrict__ upk,
                                             const float* __restrict__ upb,
                                             float* __restrict__ ws) {
    __shared__ float sd[256];
    int r = blockIdx.x, tid = threadIdx.x;
    int b = r >> 6, c = r & 63;
    const float* att = ws + WS_ATT + (size_t)r * 4096;
    const float4* xn0 = (const float4*)x + (size_t)nidx[2 * b] * 16384;
    const float4* xn1 = (const float4*)x + (size_t)nidx[2 * b + 1] * 16384;
    const float4* k4p = (const float4*)upk + c * 4;
    float ub = upb[c];
    float4 kk0 = k4p[0], kk1 = k4p[1], kk2 = k4p[2], kk3 = k4p[3];
    float s2 = 0.f, d0 = 0.f, d1 = 0.f;
    for (int it = 0; it < 64; ++it) {
        int f = it * 256 + tid;
        int rowf = f >> 6, c4 = f & 63;
        float av = att[(rowf >> 2) * 64 + c4];
        int p = rowf & 3;
        float4 kv = (p == 0) ? kk0 : ((p == 1) ? kk1 : ((p == 2) ? kk2 : kk3));
        float4 a0 = xn0[f], a1 = xn1[f];
        float u;
        u = av * kv.x + ub; s2 += u * u; d0 += u * a0.x; d1 += u * a1.x;
        u = av * kv.y + ub; s2 += u * u; d0 += u * a0.y; d1 += u * a1.y;
        u = av * kv.z + ub; s2 += u * u; d0 += u * a0.z; d1 += u * a1.z;
        u = av * kv.w + ub; s2 += u * u; d0 += u * a0.w; d1 += u * a1.w;
    }
    s2 = bsum(s2, sd, tid);
    d0 = bsum(d0, sd, tid);
    d1 = bsum(d1, sd, tid);
    if (tid == 0) {
        float nup = fmaxf(sqrtf(s2), 1e-12f);
        float n0 = fmaxf(ws[WS_NSTAT + 8 + 2 * b], 1e-12f);
        float n1 = fmaxf(ws[WS_NSTAT + 8 + 2 * b + 1], 1e-12f);
        float sim = 0.5f * (d0 / (nup * n0) + d1 / (nup * n1));
        ws[WS_FAC + r] = 2.0f - sim;
    }
}

// ---------------- K6: fused out_clu -> group conv -> 2x2 maxpool (in-thread) -> x_ds ----------------
// grid (128,4,4); 128 threads; thread owns cols {2t,2t+1} x rows {r0,r0+1}.
__global__ __launch_bounds__(128) void k_cluds(const float* __restrict__ x,
                                               const float* __restrict__ upk,
                                               const float* __restrict__ upb,
                                               const float* __restrict__ cw,
                                               const float* __restrict__ cb,
                                               float* __restrict__ ws) {
    __shared__ float wcl[256];   // clu_w[g][o][i]
    __shared__ float kup[256];   // up_k for channels g*16..g*16+15
    __shared__ float cbl[16], ubl[16], fcl[16];
    int h2 = blockIdx.x, g = blockIdx.y, b = blockIdx.z;
    int t = threadIdx.x;
    wcl[t] = cw[g * 256 + t];       wcl[t + 128] = cw[g * 256 + t + 128];
    kup[t] = upk[g * 256 + t];      kup[t + 128] = upk[g * 256 + t + 128];
    if (t < 16) {
        cbl[t] = cb[g * 16 + t];
        ubl[t] = upb[g * 16 + t];
        fcl[t] = ws[WS_FAC + b * 64 + g * 16 + t];
    }
    __syncthreads();
    int r0 = 2 * h2;
    int p0 = r0 & 3;                 // 0 or 2
    int q0 = (2 * t) & 3;            // 0 or 2
    int h_att = h2 >> 1;
    int wa = t >> 1;                 // att col for both owned cols
    const float* attb = ws + WS_ATT;
    float oc[16][4];
    #pragma unroll
    for (int i = 0; i < 16; ++i) {
        int ch = g * 16 + i;
        float av = attb[(size_t)(b * 64 + ch) * 4096 + h_att * 64 + wa];
        const float* xc = x + (size_t)(b * 64 + ch) * 65536;
        float2 x0 = *(const float2*)&xc[r0 * 256 + 2 * t];
        float2 x1 = *(const float2*)&xc[(r0 + 1) * 256 + 2 * t];
        float ub = ubl[i], fc = fcl[i];
        oc[i][0] = av * kup[i * 16 + p0 * 4 + q0]           + ub + fc * x0.x;
        oc[i][1] = av * kup[i * 16 + p0 * 4 + q0 + 1]       + ub + fc * x0.y;
        oc[i][2] = av * kup[i * 16 + (p0 + 1) * 4 + q0]     + ub + fc * x1.x;
        oc[i][3] = av * kup[i * 16 + (p0 + 1) * 4 + q0 + 1] + ub + fc * x1.y;
    }
    float* xds = ws + WS_XDS;
    #pragma unroll
    for (int o = 0; o < 16; ++o) {
        float cbv = cbl[o];
        float a0 = cbv, a1 = cbv, a2 = cbv, a3 = cbv;
        #pragma unroll
        for (int i = 0; i < 16; ++i) {
            float wv = wcl[o * 16 + i];
            a0 += wv * oc[i][0]; a1 += wv * oc[i][1];
            a2 += wv * oc[i][2]; a3 += wv * oc[i][3];
        }
        float m = fmaxf(fmaxf(a0, a1), fmaxf(a2, a3));
        xds[(size_t)((b * 64 + g * 16 + o) * 128 + h2) * 128 + t] = m;
    }
}

// ---------------- K7a: head attention partials (16 chunks per (b,nh), float4) ----------------
__global__ __launch_bounds__(256) void k_attn2a(const float* __restrict__ w2,
                                                float* __restrict__ ws) {
    __shared__ float wl2[192];
    __shared__ float ms[256], dsh[256];
    __shared__ float ns[256][17];    // padded: avoid 32-way bank conflict
    int chunk = blockIdx.x, nh = blockIdx.y, b = blockIdx.z, tid = threadIdx.x;
    if (tid < 192) wl2[tid] = w2[tid];
    __syncthreads();
    const float4* X4 = (const float4*)(ws + WS_XDS + (size_t)b * 1048576);
    int li = chunk * 256 + tid;      // float4 index within a 4096-f4 plane
    float4 sc = make_float4(0.f, 0.f, 0.f, 0.f);
    #pragma unroll
    for (int d = 0; d < 16; ++d) {
        int jq = nh * 16 + d, jk = 64 + nh * 16 + d;
        float4 q4 = X4[(size_t)(jq / 3) * 4096 + li];
        float4 k4 = X4[(size_t)(jk / 3) * 4096 + li];
        float wqk = wl2[jq] * wl2[jk] * 0.25f;
        sc.x += wqk * q4.x * k4.x; sc.y += wqk * q4.y * k4.y;
        sc.z += wqk * q4.z * k4.z; sc.w += wqk * q4.w * k4.w;
    }
    float m = fmaxf(fmaxf(sc.x, sc.y), fmaxf(sc.z, sc.w));
    float p0 = __expf(sc.x - m), p1 = __expf(sc.y - m), p2 = __expf(sc.z - m), p3 = __expf(sc.w - m);
    float den = p0 + p1 + p2 + p3;
    float num[16];
    #pragma unroll
    for (int d = 0; d < 16; ++d) {
        int jv = 128 + nh * 16 + d;
        float4 v4 = X4[(size_t)(jv / 3) * 4096 + li];
        num[d] = wl2[jv] * (p0 * v4.x + p1 * v4.y + p2 * v4.z + p3 * v4.w);
    }
    ms[tid] = m; dsh[tid] = den;
    #pragma unroll
    for (int d = 0; d < 16; ++d) ns[tid][d] = num[d];
    __syncthreads();
    for (int off = 128; off > 0; off >>= 1) {
        if (tid < off) {
            float ma = ms[tid], mb = ms[tid + off];
            float M = fmaxf(ma, mb);
            float ra = __expf(ma - M), rb = __expf(mb - M);
            dsh[tid] = dsh[tid] * ra + dsh[tid + off] * rb;
            #pragma unroll
            for (int d = 0; d < 16; ++d)
                ns[tid][d] = ns[tid][d] * ra + ns[tid + off][d] * rb;
            ms[tid] = M;
        }
        __syncthreads();
    }
    if (tid == 0) {
        float* p = ws + WS_P2 + ((size_t)(b * 4 + nh) * 16 + chunk) * 18;
        p[0] = ms[0]; p[1] = dsh[0];
        #pragma unroll
        for (int d = 0; d < 16; ++d) p[2 + d] = ns[0][d];
    }
}

// ---------------- K7b: merge attn2 partials + head math (alpha, beta) ----------------
__global__ __launch_bounds__(256) void k_tail(const float* __restrict__ bw,
                                              const float* __restrict__ bb,
                                              const float* __restrict__ cw,
                                              float* __restrict__ ws) {
    __shared__ float ohs[256], sd[256];
    int tid = threadIdx.x;
    int grp = tid >> 4;          // b*4+nh (16 groups)
    int j = tid & 15;            // chunk
    const float* p = ws + WS_P2 + ((size_t)grp * 16 + j) * 18;
    float m = p[0], den = p[1], num[16];
    #pragma unroll
    for (int d = 0; d < 16; ++d) num[d] = p[2 + d];
    #pragma unroll
    for (int mask = 1; mask <= 8; mask <<= 1) {
        float mo = __shfl_xor(m, mask);
        float dn = __shfl_xor(den, mask);
        float M = fmaxf(m, mo);
        float ra = __expf(m - M), rb = __expf(mo - M);
        den = den * ra + dn * rb;
        #pragma unroll
        for (int d = 0; d < 16; ++d)
            num[d] = num[d] * ra + __shfl_xor(num[d], mask) * rb;
        m = M;
    }
    if (j == 0) {
        int b = grp >> 2, nh = grp & 3;
        #pragma unroll
        for (int d = 0; d < 16; ++d) ohs[b * 64 + nh * 16 + d] = num[d] / den;
    }
    __syncthreads();
    int b = tid >> 6, o = tid & 63;
    float s = bb[o];
    #pragma unroll 4
    for (int c2 = 0; c2 < 64; ++c2) s += bw[o * 64 + c2] * ohs[b * 64 + c2];
    float oacc = 0.f;
    for (int u = 0; u < 4; ++u) {
        int e = tid * 4 + u;
        int g = e >> 8, oo = (e >> 4) & 15, pp = e & 15;
        float ssv = 0.f;
        #pragma unroll
        for (int i = 0; i < 16; ++i) ssv += cw[g * 256 + oo * 16 + i] * cw[g * 256 + pp * 16 + i];
        float dd = ssv - ((oo == pp) ? 1.0f : 0.0f);
        oacc += dd * dd;
    }
    float tot = bsum(oacc, sd, tid);
    float nd = fmaxf(fabsf(s) * 256.0f, 1e-12f);
    float t0 = ws[WS_NSTAT + 2 * b], t1 = ws[WS_NSTAT + 2 * b + 1];
    float n0 = fmaxf(ws[WS_NSTAT + 8 + 2 * b], 1e-12f);
    float n1 = fmaxf(ws[WS_NSTAT + 8 + 2 * b + 1], 1e-12f);
    float sim2 = (s / nd) * 0.5f * (t0 / n0 + t1 / n1);
    ws[WS_ALPHA + tid] = (1.0f - sim2) * s;
    if (tid == 0) ws[WS_BETA] = 2.0f - tot / 1024.0f;   // 1 + ortho
}

// ---------------- K8: final out = beta*out_clu + alpha ----------------
__global__ __launch_bounds__(256) void k_final(const float* __restrict__ x,
                                               const float* __restrict__ upk,
                                               const float* __restrict__ upb,
                                               const float* __restrict__ ws,
                                               float* __restrict__ out) {
    int idx = blockIdx.x * 256 + threadIdx.x;   // float4 index
    int r = idx >> 14;
    int rem = idx & 16383;
    int rowf = rem >> 6, c4 = rem & 63;
    int c = r & 63;
    float av = ws[WS_ATT + (size_t)r * 4096 + (rowf >> 2) * 64 + c4];
    int p = rowf & 3;
    float4 kv = ((const float4*)upk)[c * 4 + p];
    float ub = upb[c];
    float fac = ws[WS_FAC + r], al = ws[WS_ALPHA + r], be = ws[WS_BETA];
    float4 xv = ((const float4*)x)[idx];
    float4 o;
    o.x = be * (av * kv.x + ub + fac * xv.x) + al;
    o.y = be * (av * kv.y + ub + fac * xv.y) + al;
    o.z = be * (av * kv.z + ub + fac * xv.z) + al;
    o.w = be * (av * kv.w + ub + fac * xv.w) + al;
    ((float4*)out)[idx] = o;
}

extern "C" void kernel_launch(void* const* d_in, const int* in_sizes, int n_in,
                              void* d_out, int out_size, void* d_ws, size_t ws_size,
                              hipStream_t stream) {
    const float* x      = (const float*)d_in[0];
    const int*   labels = (const int*)d_in[1];
    const int*   nidx   = (const int*)d_in[2];
    const float* w1     = (const float*)d_in[3];
    const float* b1     = (const float*)d_in[4];
    const float* upk    = (const float*)d_in[5];
    const float* upb    = (const float*)d_in[6];
    const float* cw     = (const float*)d_in[7];
    const float* cb     = (const float*)d_in[8];
    const float* w2     = (const float*)d_in[9];
    const float* bw     = (const float*)d_in[10];
    const float* bb     = (const float*)d_in[11];
    float* ws  = (float*)d_ws;
    float* out = (float*)d_out;

    hipLaunchKernelGGL(k_pool4,  dim3(256),        dim3(256), 0, stream, x, nidx, ws);
    hipLaunchKernelGGL(k_gram,   dim3(2, 2, 64),   dim3(256), 0, stream, ws);
    hipLaunchKernelGGL(k_attn1,  dim3(256),        dim3(256), 0, stream, labels, w1, b1, ws);
    hipLaunchKernelGGL(k_attmm,  dim3(64, 4),      dim3(256), 0, stream, ws);
    hipLaunchKernelGGL(k_sim,    dim3(256),        dim3(256), 0, stream, x, nidx, upk, upb, ws);
    hipLaunchKernelGGL(k_cluds,  dim3(128, 4, 4),  dim3(128), 0, stream, x, upk, upb, cw, cb, ws);
    hipLaunchKernelGGL(k_attn2a, dim3(16, 4, 4),   dim3(256), 0, stream, w2, ws);
    hipLaunchKernelGGL(k_tail,   dim3(1),          dim3(256), 0, stream, bw, bb, cw, ws);
    hipLaunchKernelGGL(k_final,  dim3(16384),      dim3(256), 0, stream, x, upk, upb, ws, out);
}